// Round 2
// baseline (702.558 us; speedup 1.0000x reference)
//
#include <hip/hip_runtime.h>
#include <hip/hip_bf16.h>

#define NN 20000
#define EE 320000
#define GG 256

__device__ __forceinline__ float lanebc(float v, int l){
  return __uint_as_float(__builtin_amdgcn_readlane(__float_as_uint(v), (unsigned)l));
}
__device__ __forceinline__ float wave_sum(float v){
  #pragma unroll
  for(int m=32;m>0;m>>=1) v += __shfl_xor(v, m, 64);
  return v;
}

// ---------------- node MLP: h0[N,64] ----------------
__global__ void k_node_mlp(const float* __restrict__ x, const float* __restrict__ Wcat,
                           const float* __restrict__ bcat, const float* __restrict__ Wini,
                           const float* __restrict__ bini, float* __restrict__ h0){
  const int t = blockIdx.x;
  const int c = threadIdx.x;   // 64
  __shared__ float xs[24];
  __shared__ float s[32];
  if (c < 24) xs[c] = x[t*24 + c];
  __syncthreads();
  if (c < 32){
    float a = bcat[c];
    #pragma unroll
    for(int k=0;k<16;k++) a += xs[k]*Wcat[k*32 + c];
    s[c] = fmaxf(a, 0.f);
  }
  __syncthreads();
  float a = bini[c];
  #pragma unroll
  for(int k=0;k<8;k++)  a += xs[16+k]*Wini[k*64 + c];
  #pragma unroll
  for(int k=0;k<32;k++) a += s[k]*Wini[(8+k)*64 + c];
  h0[t*64 + c] = fmaxf(a, 0.f);
}

// ---------------- edge embedding sums + in-degree ----------------
__global__ void k_edge_ee(const int* __restrict__ ei, const float* __restrict__ ea,
                          const float* __restrict__ We, const float* __restrict__ be,
                          float* __restrict__ loop, int* __restrict__ cnt){
  const int g = blockIdx.x*8 + (threadIdx.x>>5);
  const int k = threadIdx.x & 31;
  if (g >= EE) return;
  const int t = ei[EE + g];
  float a = be[k];
  #pragma unroll
  for(int j=0;j<9;j++) a += ea[g*9 + j] * We[j*32 + k];
  atomicAdd(&loop[t*32 + k], a);
  if (k == 0) atomicAdd(&cnt[t], 1);
}

// ---------------- CSR bucket allocation (order-free, no scan) ----------------
__global__ void k_alloc(const int* __restrict__ cnt, int* __restrict__ start, int* __restrict__ counter){
  int i = blockIdx.x*blockDim.x + threadIdx.x;
  if (i < NN) start[i] = atomicAdd(counter, cnt[i]);
}

__global__ void k_scatter(const int* __restrict__ ei, const int* __restrict__ start,
                          int* __restrict__ fill, int* __restrict__ csr){
  int e = blockIdx.x*blockDim.x + threadIdx.x;
  if (e >= EE) return;
  int t = ei[EE + e];
  int p = start[t] + atomicAdd(&fill[t], 1);
  csr[p] = e;
}

__global__ void k_loop_div(float* __restrict__ loop, const int* __restrict__ cnt){
  int i = blockIdx.x*blockDim.x + threadIdx.x;
  if (i >= NN*32) return;
  float d = fmaxf((float)cnt[i>>5], 1.f);
  loop[i] = loop[i] / d;
}

// ---------------- xl/xr transform, layer1: [N,64]@[64,256], 8 nodes per block ----------------
__global__ void k_xlxr1(const float* __restrict__ h0, const float* __restrict__ Wl,
                        const float* __restrict__ bl, const float* __restrict__ Wr,
                        const float* __restrict__ br, float* __restrict__ xl, float* __restrict__ xr){
  const int n0 = blockIdx.x*8;
  __shared__ __align__(16) float hsT[64][8];
  for(int i=threadIdx.x;i<512;i+=256){ int n=i>>6, k=i&63; hsT[k][n] = h0[(n0+n)*64 + k]; }
  __syncthreads();
  const int c = threadIdx.x;   // 256
  float accl[8], accr[8];
  const float blv = bl[c], brv = br[c];
  #pragma unroll
  for(int n=0;n<8;n++){ accl[n]=blv; accr[n]=brv; }
  for(int k=0;k<64;k++){
    const float wl = Wl[k*256 + c];
    const float wr = Wr[k*256 + c];
    const float4 ha = *(const float4*)&hsT[k][0];
    const float4 hb = *(const float4*)&hsT[k][4];
    accl[0]+=ha.x*wl; accr[0]+=ha.x*wr; accl[1]+=ha.y*wl; accr[1]+=ha.y*wr;
    accl[2]+=ha.z*wl; accr[2]+=ha.z*wr; accl[3]+=ha.w*wl; accr[3]+=ha.w*wr;
    accl[4]+=hb.x*wl; accr[4]+=hb.x*wr; accl[5]+=hb.y*wl; accr[5]+=hb.y*wr;
    accl[6]+=hb.z*wl; accr[6]+=hb.z*wr; accl[7]+=hb.w*wl; accr[7]+=hb.w*wr;
  }
  #pragma unroll
  for(int n=0;n<8;n++){ xl[(n0+n)*256 + c] = accl[n]; xr[(n0+n)*256 + c] = accr[n]; }
}

// ---------------- xl/xr transform, layer2: [N,256]@[256,64], 8 nodes per block ----------------
__global__ void k_xlxr2(const float* __restrict__ h1, const float* __restrict__ Wl,
                        const float* __restrict__ bl, const float* __restrict__ Wr,
                        const float* __restrict__ br, float* __restrict__ xl, float* __restrict__ xr){
  const int n0 = blockIdx.x*8;
  __shared__ __align__(16) float hsT[256][8];
  for(int i=threadIdx.x;i<2048;i+=64){ int n=i>>8, k=i&255; hsT[k][n] = h1[(n0+n)*256 + k]; }
  __syncthreads();
  const int c = threadIdx.x;   // 64
  float accl[8], accr[8];
  const float blv = bl[c], brv = br[c];
  #pragma unroll
  for(int n=0;n<8;n++){ accl[n]=blv; accr[n]=brv; }
  for(int k=0;k<256;k++){
    const float wl = Wl[k*64 + c];
    const float wr = Wr[k*64 + c];
    const float4 ha = *(const float4*)&hsT[k][0];
    const float4 hb = *(const float4*)&hsT[k][4];
    accl[0]+=ha.x*wl; accr[0]+=ha.x*wr; accl[1]+=ha.y*wl; accr[1]+=ha.y*wr;
    accl[2]+=ha.z*wl; accr[2]+=ha.z*wr; accl[3]+=ha.w*wl; accr[3]+=ha.w*wr;
    accl[4]+=hb.x*wl; accr[4]+=hb.x*wr; accl[5]+=hb.y*wl; accr[5]+=hb.y*wr;
    accl[6]+=hb.z*wl; accr[6]+=hb.z*wr; accl[7]+=hb.w*wl; accr[7]+=hb.w*wr;
  }
  #pragma unroll
  for(int n=0;n<8;n++){ xl[(n0+n)*64 + c] = accl[n]; xr[(n0+n)*64 + c] = accr[n]; }
}

// ---------------- GATv2 per-node kernel. One wave per (node, head). No barriers. ----------------
template<int HEADS>
__global__ void k_gat(const int* __restrict__ ei, const float* __restrict__ ea,
                      const float* __restrict__ Weg, const float* __restrict__ beg,
                      const float* __restrict__ loop, const int* __restrict__ cnt,
                      const int* __restrict__ start, const int* __restrict__ csr,
                      const float* __restrict__ xl, const float* __restrict__ xr,
                      const float* __restrict__ WeL, const float* __restrict__ att,
                      const float* __restrict__ bias, float* __restrict__ esc,
                      float* __restrict__ hout)
{
  const int t    = blockIdx.x;
  const int lane = threadIdx.x & 63;
  const int w    = threadIdx.x >> 6;
  const int F    = HEADS*64;
  const int c    = w*64 + lane;

  float reg[32];                            // We column c, in VGPRs
  #pragma unroll
  for(int k=0;k<32;k++) reg[k] = WeL[k*F + c];
  const int kk = lane & 31;
  float wE[9];                              // W_e column kk (edge-attr -> ee)
  #pragma unroll
  for(int j=0;j<9;j++) wE[j] = Weg[j*32 + kk];
  const float beK  = beg[kk];
  const float attc = att[c];
  const float xrv  = xr[t*F + c];
  const float xlS  = xl[t*F + c];
  const int st = start[t];
  const int dg = cnt[t];

  // prefetch edge ids + sources into lane slots (covers deg<=64)
  int eL = 0, sL = 0;
  if (lane < dg) { eL = csr[st + lane]; sL = ei[eL]; }

  // ---- self-loop score ----
  float eevS = loop[t*32 + kk];
  float ep = 0.f;
  #pragma unroll
  for(int k=0;k<32;k++) ep += lanebc(eevS, k) * reg[k];
  float m = xlS + xrv + ep;
  m = (m >= 0.f) ? m : 0.2f*m;
  const float sSelf = wave_sum(attc * m);
  float mx = sSelf;
  float sreg = 0.f;

  // ---- pass 1: scores + running max ----
  for(int i=0;i<dg;i++){
    const int e = (i < 64) ? __shfl(eL, i, 64) : csr[st + i];
    float eev = beK;
    #pragma unroll
    for(int j=0;j<9;j++) eev += ea[e*9 + j] * wE[j];
    const int s = (i < 64) ? __shfl(sL, i, 64) : ei[e];
    float epv = 0.f;
    #pragma unroll
    for(int k=0;k<32;k++) epv += lanebc(eev, k) * reg[k];
    float mm = xl[s*F + c] + xrv + epv;
    mm = (mm >= 0.f) ? mm : 0.2f*mm;
    const float se = wave_sum(attc * mm);
    if (i < 64) { if (lane == i) sreg = se; }
    else if (lane == 0) esc[e*HEADS + w] = se;
    mx = fmaxf(mx, se);
  }

  // ---- pass 2: softmax + aggregate ----
  float p   = __expf(sSelf - mx);
  float den = p;
  float acc = p * xlS;
  for(int i=0;i<dg;i++){
    const int e = (i < 64) ? __shfl(eL, i, 64) : csr[st + i];
    const int s = (i < 64) ? __shfl(sL, i, 64) : ei[e];
    const float se = (i < 64) ? lanebc(sreg, i) : esc[e*HEADS + w];
    const float pp = __expf(se - mx);
    den += pp;
    acc += pp * xl[s*F + c];
  }
  const float o = acc / (den + 1e-16f) + bias[c];
  hout[t*F + c] = (o > 0.f) ? o : expm1f(o);
}

// ---------------- graph mean-pool + output projection ----------------
__global__ void k_pool(const float* __restrict__ h2, const int* __restrict__ batch,
                       float* __restrict__ pooled, int* __restrict__ gcnt){
  int i = blockIdx.x*blockDim.x + threadIdx.x;
  if (i >= NN*64) return;
  int node = i >> 6, c = i & 63;
  int g = batch[node];
  atomicAdd(&pooled[g*64 + c], h2[i]);
  if (c == 0) atomicAdd(&gcnt[g], 1);
}

__global__ void k_out(const float* __restrict__ pooled, const int* __restrict__ gcnt,
                      const float* __restrict__ Wout, const float* __restrict__ bout,
                      float* __restrict__ out){
  int g = blockIdx.x, o = threadIdx.x;   // 128
  float a = 0.f;
  for(int k=0;k<64;k++) a += pooled[g*64 + k] * Wout[k*128 + o];
  float inv = 1.f / fmaxf((float)gcnt[g], 1.f);
  out[g*128 + o] = a*inv + bout[o];
}

extern "C" void kernel_launch(void* const* d_in, const int* in_sizes, int n_in,
                              void* d_out, int out_size, void* d_ws, size_t ws_size,
                              hipStream_t stream) {
  const float* x    = (const float*)d_in[0];
  const int*   ei   = (const int*)  d_in[1];
  const float* ea   = (const float*)d_in[2];
  const int*   batch= (const int*)  d_in[3];
  const float* Wcat = (const float*)d_in[4];
  const float* bcat = (const float*)d_in[5];
  const float* We   = (const float*)d_in[6];
  const float* be   = (const float*)d_in[7];
  const float* Wini = (const float*)d_in[8];
  const float* bini = (const float*)d_in[9];
  const float* Wl1  = (const float*)d_in[10];
  const float* bl1  = (const float*)d_in[11];
  const float* Wr1  = (const float*)d_in[12];
  const float* br1  = (const float*)d_in[13];
  const float* We1  = (const float*)d_in[14];
  const float* att1 = (const float*)d_in[15];
  const float* bias1= (const float*)d_in[16];
  const float* Wl2  = (const float*)d_in[17];
  const float* bl2  = (const float*)d_in[18];
  const float* Wr2  = (const float*)d_in[19];
  const float* br2  = (const float*)d_in[20];
  const float* We2  = (const float*)d_in[21];
  const float* att2 = (const float*)d_in[22];
  const float* bias2= (const float*)d_in[23];
  const float* Wout = (const float*)d_in[24];
  const float* bout = (const float*)d_in[25];
  float* out = (float*)d_out;
  char* ws = (char*)d_ws;

  size_t off = 0;
  auto alloc = [&](size_t bytes)->char*{ char* p = ws + off; off += (bytes + 255) & ~(size_t)255; return p; };
  float* h0    = (float*)alloc((size_t)NN*64*4);
  float* loop  = (float*)alloc((size_t)NN*32*4);
  float* xl1   = (float*)alloc((size_t)NN*256*4);
  float* xr1   = (float*)alloc((size_t)NN*256*4);
  float* h1    = (float*)alloc((size_t)NN*256*4);
  float* xl2   = (float*)alloc((size_t)NN*64*4);
  float* xr2   = (float*)alloc((size_t)NN*64*4);
  float* h2    = (float*)alloc((size_t)NN*64*4);
  float* esc   = (float*)alloc((size_t)EE*4*4);
  int*   cnt   = (int*)  alloc((size_t)NN*4);
  int*   start = (int*)  alloc((size_t)NN*4);
  int*   fill  = (int*)  alloc((size_t)NN*4);
  int*   csr   = (int*)  alloc((size_t)EE*4);
  int*   counter = (int*)alloc(256);
  float* pooled  = (float*)alloc((size_t)GG*64*4);
  int*   gcnt    = (int*)  alloc((size_t)GG*4);

  hipMemsetAsync(loop,    0, (size_t)NN*32*4, stream);
  hipMemsetAsync(cnt,     0, (size_t)NN*4,    stream);
  hipMemsetAsync(fill,    0, (size_t)NN*4,    stream);
  hipMemsetAsync(counter, 0, 256,             stream);
  hipMemsetAsync(pooled,  0, (size_t)GG*64*4, stream);
  hipMemsetAsync(gcnt,    0, (size_t)GG*4,    stream);

  k_node_mlp<<<NN, 64, 0, stream>>>(x, Wcat, bcat, Wini, bini, h0);
  k_edge_ee <<<EE/8, 256, 0, stream>>>(ei, ea, We, be, loop, cnt);
  k_alloc   <<<(NN+255)/256, 256, 0, stream>>>(cnt, start, counter);
  k_scatter <<<(EE+255)/256, 256, 0, stream>>>(ei, start, fill, csr);
  k_loop_div<<<(NN*32+255)/256, 256, 0, stream>>>(loop, cnt);
  k_xlxr1   <<<NN/8, 256, 0, stream>>>(h0, Wl1, bl1, Wr1, br1, xl1, xr1);
  k_gat<4>  <<<NN, 256, 0, stream>>>(ei, ea, We, be, loop, cnt, start, csr,
                                     xl1, xr1, We1, att1, bias1, esc, h1);
  k_xlxr2   <<<NN/8, 64, 0, stream>>>(h1, Wl2, bl2, Wr2, br2, xl2, xr2);
  k_gat<1>  <<<NN, 64, 0, stream>>>(ei, ea, We, be, loop, cnt, start, csr,
                                    xl2, xr2, We2, att2, bias2, esc, h2);
  k_pool    <<<(NN*64+255)/256, 256, 0, stream>>>(h2, batch, pooled, gcnt);
  k_out     <<<GG, 128, 0, stream>>>(pooled, gcnt, Wout, bout, out);
}

// Round 3
// 445.914 us; speedup vs baseline: 1.5755x; 1.5755x over previous
//
#include <hip/hip_runtime.h>
#include <hip/hip_bf16.h>

#define NN 20000
#define EE 320000
#define GG 256

__device__ __forceinline__ float lanebc(float v, int l){
  return __uint_as_float(__builtin_amdgcn_readlane(__float_as_uint(v), (unsigned)l));
}
__device__ __forceinline__ float wave_sum(float v){
  #pragma unroll
  for(int m=32;m>0;m>>=1) v += __shfl_xor(v, m, 64);
  return v;
}
__device__ __forceinline__ float wave_max(float v){
  #pragma unroll
  for(int m=32;m>0;m>>=1) v = fmaxf(v, __shfl_xor(v, m, 64));
  return v;
}

// ---------------- node MLP: h0[N,64] ----------------
__global__ void k_node_mlp(const float* __restrict__ x, const float* __restrict__ Wcat,
                           const float* __restrict__ bcat, const float* __restrict__ Wini,
                           const float* __restrict__ bini, float* __restrict__ h0){
  const int t = blockIdx.x;
  const int c = threadIdx.x;   // 64
  __shared__ float xs[24];
  __shared__ float s[32];
  if (c < 24) xs[c] = x[t*24 + c];
  __syncthreads();
  if (c < 32){
    float a = bcat[c];
    #pragma unroll
    for(int k=0;k<16;k++) a += xs[k]*Wcat[k*32 + c];
    s[c] = fmaxf(a, 0.f);
  }
  __syncthreads();
  float a = bini[c];
  #pragma unroll
  for(int k=0;k<8;k++)  a += xs[16+k]*Wini[k*64 + c];
  #pragma unroll
  for(int k=0;k<32;k++) a += s[k]*Wini[(8+k)*64 + c];
  h0[t*64 + c] = fmaxf(a, 0.f);
}

// ---------------- edge embedding: materialize ee[E,32], loop sums, in-degree ----------------
__global__ void k_edge_ee(const int* __restrict__ ei, const float* __restrict__ ea,
                          const float* __restrict__ We, const float* __restrict__ be,
                          float* __restrict__ ee, float* __restrict__ loop, int* __restrict__ cnt){
  const int g = blockIdx.x*8 + (threadIdx.x>>5);
  const int k = threadIdx.x & 31;
  if (g >= EE) return;
  const int t = ei[EE + g];
  float a = be[k];
  #pragma unroll
  for(int j=0;j<9;j++) a += ea[g*9 + j] * We[j*32 + k];
  ee[(size_t)g*32 + k] = a;
  atomicAdd(&loop[t*32 + k], a);
  if (k == 0) atomicAdd(&cnt[t], 1);
}

// ---------------- CSR bucket allocation (order-free, no scan) ----------------
__global__ void k_alloc(const int* __restrict__ cnt, int* __restrict__ start, int* __restrict__ counter){
  int i = blockIdx.x*blockDim.x + threadIdx.x;
  if (i < NN) start[i] = atomicAdd(counter, cnt[i]);
}

__global__ void k_scatter(const int* __restrict__ ei, const int* __restrict__ start,
                          int* __restrict__ fill, int* __restrict__ csr,
                          int* __restrict__ srcp, int* __restrict__ tgtp){
  int e = blockIdx.x*blockDim.x + threadIdx.x;
  if (e >= EE) return;
  int t = ei[EE + e];
  int p = start[t] + atomicAdd(&fill[t], 1);
  csr[p] = e;
  srcp[p] = ei[e];
  tgtp[p] = t;
}

__global__ void k_loop_div(float* __restrict__ loop, const int* __restrict__ cnt){
  int i = blockIdx.x*blockDim.x + threadIdx.x;
  if (i >= NN*32) return;
  float d = fmaxf((float)cnt[i>>5], 1.f);
  loop[i] = loop[i] / d;
}

// ---------------- xl/xr transform, layer1: [N,64]@[64,256] ----------------
__global__ void k_xlxr1(const float* __restrict__ h0, const float* __restrict__ Wl,
                        const float* __restrict__ bl, const float* __restrict__ Wr,
                        const float* __restrict__ br, float* __restrict__ xl, float* __restrict__ xr){
  const int n0 = blockIdx.x*8;
  __shared__ __align__(16) float hsT[64][8];
  for(int i=threadIdx.x;i<512;i+=256){ int n=i>>6, k=i&63; hsT[k][n] = h0[(n0+n)*64 + k]; }
  __syncthreads();
  const int c = threadIdx.x;   // 256
  float accl[8], accr[8];
  const float blv = bl[c], brv = br[c];
  #pragma unroll
  for(int n=0;n<8;n++){ accl[n]=blv; accr[n]=brv; }
  for(int k=0;k<64;k++){
    const float wl = Wl[k*256 + c];
    const float wr = Wr[k*256 + c];
    const float4 ha = *(const float4*)&hsT[k][0];
    const float4 hb = *(const float4*)&hsT[k][4];
    accl[0]+=ha.x*wl; accr[0]+=ha.x*wr; accl[1]+=ha.y*wl; accr[1]+=ha.y*wr;
    accl[2]+=ha.z*wl; accr[2]+=ha.z*wr; accl[3]+=ha.w*wl; accr[3]+=ha.w*wr;
    accl[4]+=hb.x*wl; accr[4]+=hb.x*wr; accl[5]+=hb.y*wl; accr[5]+=hb.y*wr;
    accl[6]+=hb.z*wl; accr[6]+=hb.z*wr; accl[7]+=hb.w*wl; accr[7]+=hb.w*wr;
  }
  #pragma unroll
  for(int n=0;n<8;n++){ xl[(n0+n)*256 + c] = accl[n]; xr[(n0+n)*256 + c] = accr[n]; }
}

// ---------------- xl/xr transform, layer2: [N,256]@[256,64] ----------------
__global__ void k_xlxr2(const float* __restrict__ h1, const float* __restrict__ Wl,
                        const float* __restrict__ bl, const float* __restrict__ Wr,
                        const float* __restrict__ br, float* __restrict__ xl, float* __restrict__ xr){
  const int n0 = blockIdx.x*8;
  __shared__ __align__(16) float hsT[256][8];
  for(int i=threadIdx.x;i<2048;i+=64){ int n=i>>8, k=i&255; hsT[k][n] = h1[(n0+n)*256 + k]; }
  __syncthreads();
  const int c = threadIdx.x;   // 64
  float accl[8], accr[8];
  const float blv = bl[c], brv = br[c];
  #pragma unroll
  for(int n=0;n<8;n++){ accl[n]=blv; accr[n]=brv; }
  for(int k=0;k<256;k++){
    const float wl = Wl[k*64 + c];
    const float wr = Wr[k*64 + c];
    const float4 ha = *(const float4*)&hsT[k][0];
    const float4 hb = *(const float4*)&hsT[k][4];
    accl[0]+=ha.x*wl; accr[0]+=ha.x*wr; accl[1]+=ha.y*wl; accr[1]+=ha.y*wr;
    accl[2]+=ha.z*wl; accr[2]+=ha.z*wr; accl[3]+=ha.w*wl; accr[3]+=ha.w*wr;
    accl[4]+=hb.x*wl; accr[4]+=hb.x*wr; accl[5]+=hb.y*wl; accr[5]+=hb.y*wr;
    accl[6]+=hb.z*wl; accr[6]+=hb.z*wr; accl[7]+=hb.w*wl; accr[7]+=hb.w*wr;
  }
  #pragma unroll
  for(int n=0;n<8;n++){ xl[(n0+n)*64 + c] = accl[n]; xr[(n0+n)*64 + c] = accr[n]; }
}

// ---------------- edge-parallel GATv2 scores, CSR-position order ----------------
// 64 edges/block, 256 threads. Register-blocked ep-GEMM + fused leaky/att epilogue.
template<int F>
__global__ __launch_bounds__(256) void k_score(const float* __restrict__ ee, const int* __restrict__ csr,
                        const int* __restrict__ srcp, const int* __restrict__ tgtp,
                        const float* __restrict__ xl, const float* __restrict__ xr,
                        const float* __restrict__ We, const float* __restrict__ att,
                        float* __restrict__ esc)
{
  constexpr int HP  = (F == 256) ? 2 : 1;   // channel passes
  constexpr int CPL = (F == 256) ? 8 : 4;   // channels per lane per pass
  const int tid  = threadIdx.x;
  const int lane = tid & 63;
  const int w    = tid >> 6;
  const int p0   = blockIdx.x * 64;

  __shared__ float ee_sT[32][64];
  __shared__ float We_s[32*F];
  __shared__ int src_s[64], tgt_s[64];

  if (tid < 64) { src_s[tid] = srcp[p0+tid]; tgt_s[tid] = tgtp[p0+tid]; }
  {
    const int e = csr[p0 + lane];
    const float4 a = *(const float4*)(ee + (size_t)e*32 + w*8);
    const float4 b = *(const float4*)(ee + (size_t)e*32 + w*8 + 4);
    ee_sT[w*8+0][lane]=a.x; ee_sT[w*8+1][lane]=a.y; ee_sT[w*8+2][lane]=a.z; ee_sT[w*8+3][lane]=a.w;
    ee_sT[w*8+4][lane]=b.x; ee_sT[w*8+5][lane]=b.y; ee_sT[w*8+6][lane]=b.z; ee_sT[w*8+7][lane]=b.w;
  }
  for (int i = tid; i < (32*F)/4; i += 256) ((float4*)We_s)[i] = ((const float4*)We)[i];
  __syncthreads();

  const int g = lane >> 4, t = lane & 15;
  const int eb = w*16 + g*4;     // this lane's 4 edges

  #pragma unroll
  for (int hp = 0; hp < HP; ++hp) {
    const int c = hp*(F/HP) + t*CPL;
    float acc[4][CPL];
    #pragma unroll
    for (int j=0;j<4;j++)
      #pragma unroll
      for(int q=0;q<CPL;q++) acc[j][q]=0.f;
    #pragma unroll 4
    for (int k=0;k<32;k++){
      const float4 ev = *(const float4*)&ee_sT[k][eb];
      float wv[CPL];
      *(float4*)&wv[0] = *(const float4*)&We_s[k*F + c];
      if (CPL==8) *(float4*)&wv[4] = *(const float4*)&We_s[k*F + c + 4];
      #pragma unroll
      for (int q=0;q<CPL;q++){
        acc[0][q] += ev.x*wv[q]; acc[1][q] += ev.y*wv[q];
        acc[2][q] += ev.z*wv[q]; acc[3][q] += ev.w*wv[q];
      }
    }
    float attv[CPL];
    *(float4*)&attv[0] = *(const float4*)&att[c];
    if (CPL==8) *(float4*)&attv[4] = *(const float4*)&att[c+4];
    float partial[4];
    #pragma unroll
    for (int j=0;j<4;j++){
      const int s  = src_s[eb+j];
      const int tg = tgt_s[eb+j];
      float xlv[CPL], xrv[CPL];
      *(float4*)&xlv[0] = *(const float4*)&xl[(size_t)s*F + c];
      *(float4*)&xrv[0] = *(const float4*)&xr[(size_t)tg*F + c];
      if (CPL==8){
        *(float4*)&xlv[4] = *(const float4*)&xl[(size_t)s*F + c + 4];
        *(float4*)&xrv[4] = *(const float4*)&xr[(size_t)tg*F + c + 4];
      }
      float sum = 0.f;
      #pragma unroll
      for (int q=0;q<CPL;q++){
        float m = acc[j][q] + xlv[q] + xrv[q];
        m = (m >= 0.f) ? m : 0.2f*m;
        sum += attv[q]*m;
      }
      partial[j] = sum;
    }
    #pragma unroll
    for (int j=0;j<4;j++){
      partial[j] += __shfl_xor(partial[j], 1, 64);
      partial[j] += __shfl_xor(partial[j], 2, 64);
      partial[j] += __shfl_xor(partial[j], 4, 64);
      if (F==64) partial[j] += __shfl_xor(partial[j], 8, 64);
    }
    if (F==256){
      if ((t & 7) == 0){
        const int h = hp*2 + (t>>3);
        #pragma unroll
        for (int j=0;j<4;j++) esc[(size_t)h*EE + p0 + eb + j] = partial[j];
      }
    } else {
      if (t == 0){
        #pragma unroll
        for (int j=0;j<4;j++) esc[p0 + eb + j] = partial[j];
      }
    }
  }
}

// ---------------- per-node softmax + aggregate (scores precomputed) ----------------
template<int HEADS>
__global__ void k_agg(const float* __restrict__ loop, const int* __restrict__ cnt,
                      const int* __restrict__ start, const int* __restrict__ srcp,
                      const float* __restrict__ xl, const float* __restrict__ xr,
                      const float* __restrict__ We, const float* __restrict__ att,
                      const float* __restrict__ bias, const float* __restrict__ esc,
                      float* __restrict__ hout)
{
  const int t    = blockIdx.x;
  const int lane = threadIdx.x & 63;
  const int w    = threadIdx.x >> 6;
  const int F    = HEADS*64;
  const int c    = w*64 + lane;
  const int st = start[t], dg = cnt[t];
  const float* escw = esc + (size_t)w*EE;

  const float xlS = xl[(size_t)t*F + c];
  const float xrv = xr[(size_t)t*F + c];

  // self-loop score (fp32, loop = mean incoming ee)
  const int kk = lane & 31;
  const float eevS = loop[t*32 + kk];
  float ep = 0.f;
  #pragma unroll
  for (int k=0;k<32;k++) ep += lanebc(eevS,k) * We[k*F + c];
  float m = xlS + xrv + ep;
  m = (m >= 0.f) ? m : 0.2f*m;
  const float sSelf = wave_sum(att[c]*m);

  int sL = 0; float escv = -1e30f;
  if (lane < dg){ sL = srcp[st+lane]; escv = escw[st+lane]; }
  float mx = fmaxf(wave_max(escv), sSelf);
  for (int i=64;i<dg;i+=64){
    float v = (i+lane<dg) ? escw[st+i+lane] : -1e30f;
    mx = fmaxf(mx, wave_max(v));
  }
  const float pSelf = __expf(sSelf - mx);
  float preg = (lane < dg) ? __expf(escv - mx) : 0.f;
  float den = wave_sum(preg) + pSelf;
  float acc = pSelf * xlS;
  const int d1 = min(dg, 64);
  for (int i=0;i<d1;i++){
    const int s = __shfl(sL, i, 64);
    const float pp = lanebc(preg, i);
    acc += pp * xl[(size_t)s*F + c];
  }
  for (int i=64;i<dg;i++){
    const float pp = __expf(escw[st+i] - mx);
    den += pp;
    acc += pp * xl[(size_t)srcp[st+i]*F + c];
  }
  const float o = acc/(den + 1e-16f) + bias[c];
  hout[(size_t)t*F + c] = (o > 0.f) ? o : expm1f(o);
}

// ---------------- graph mean-pool + output projection ----------------
__global__ void k_pool(const float* __restrict__ h2, const int* __restrict__ batch,
                       float* __restrict__ pooled, int* __restrict__ gcnt){
  int i = blockIdx.x*blockDim.x + threadIdx.x;
  if (i >= NN*64) return;
  int node = i >> 6, c = i & 63;
  int g = batch[node];
  atomicAdd(&pooled[g*64 + c], h2[i]);
  if (c == 0) atomicAdd(&gcnt[g], 1);
}

__global__ void k_out(const float* __restrict__ pooled, const int* __restrict__ gcnt,
                      const float* __restrict__ Wout, const float* __restrict__ bout,
                      float* __restrict__ out){
  int g = blockIdx.x, o = threadIdx.x;   // 128
  float a = 0.f;
  for(int k=0;k<64;k++) a += pooled[g*64 + k] * Wout[k*128 + o];
  float inv = 1.f / fmaxf((float)gcnt[g], 1.f);
  out[g*128 + o] = a*inv + bout[o];
}

extern "C" void kernel_launch(void* const* d_in, const int* in_sizes, int n_in,
                              void* d_out, int out_size, void* d_ws, size_t ws_size,
                              hipStream_t stream) {
  const float* x    = (const float*)d_in[0];
  const int*   ei   = (const int*)  d_in[1];
  const float* ea   = (const float*)d_in[2];
  const int*   batch= (const int*)  d_in[3];
  const float* Wcat = (const float*)d_in[4];
  const float* bcat = (const float*)d_in[5];
  const float* We   = (const float*)d_in[6];
  const float* be   = (const float*)d_in[7];
  const float* Wini = (const float*)d_in[8];
  const float* bini = (const float*)d_in[9];
  const float* Wl1  = (const float*)d_in[10];
  const float* bl1  = (const float*)d_in[11];
  const float* Wr1  = (const float*)d_in[12];
  const float* br1  = (const float*)d_in[13];
  const float* We1  = (const float*)d_in[14];
  const float* att1 = (const float*)d_in[15];
  const float* bias1= (const float*)d_in[16];
  const float* Wl2  = (const float*)d_in[17];
  const float* bl2  = (const float*)d_in[18];
  const float* Wr2  = (const float*)d_in[19];
  const float* br2  = (const float*)d_in[20];
  const float* We2  = (const float*)d_in[21];
  const float* att2 = (const float*)d_in[22];
  const float* bias2= (const float*)d_in[23];
  const float* Wout = (const float*)d_in[24];
  const float* bout = (const float*)d_in[25];
  float* out = (float*)d_out;
  char* ws = (char*)d_ws;

  size_t off = 0;
  auto alloc = [&](size_t bytes)->char*{ char* p = ws + off; off += (bytes + 255) & ~(size_t)255; return p; };
  float* h0    = (float*)alloc((size_t)NN*64*4);
  float* loop  = (float*)alloc((size_t)NN*32*4);
  float* xl1   = (float*)alloc((size_t)NN*256*4);
  float* xr1   = (float*)alloc((size_t)NN*256*4);
  float* h1    = (float*)alloc((size_t)NN*256*4);
  float* xl2   = (float*)alloc((size_t)NN*64*4);
  float* xr2   = (float*)alloc((size_t)NN*64*4);
  float* h2    = (float*)alloc((size_t)NN*64*4);
  float* ee    = (float*)alloc((size_t)EE*32*4);
  float* esc   = (float*)alloc((size_t)EE*4*4);
  int*   cnt   = (int*)  alloc((size_t)NN*4);
  int*   start = (int*)  alloc((size_t)NN*4);
  int*   fill  = (int*)  alloc((size_t)NN*4);
  int*   csr   = (int*)  alloc((size_t)EE*4);
  int*   srcp  = (int*)  alloc((size_t)EE*4);
  int*   tgtp  = (int*)  alloc((size_t)EE*4);
  int*   counter = (int*)alloc(256);
  float* pooled  = (float*)alloc((size_t)GG*64*4);
  int*   gcnt    = (int*)  alloc((size_t)GG*4);

  hipMemsetAsync(loop,    0, (size_t)NN*32*4, stream);
  hipMemsetAsync(cnt,     0, (size_t)NN*4,    stream);
  hipMemsetAsync(fill,    0, (size_t)NN*4,    stream);
  hipMemsetAsync(counter, 0, 256,             stream);
  hipMemsetAsync(pooled,  0, (size_t)GG*64*4, stream);
  hipMemsetAsync(gcnt,    0, (size_t)GG*4,    stream);

  k_node_mlp<<<NN, 64, 0, stream>>>(x, Wcat, bcat, Wini, bini, h0);
  k_edge_ee <<<EE/8, 256, 0, stream>>>(ei, ea, We, be, ee, loop, cnt);
  k_alloc   <<<(NN+255)/256, 256, 0, stream>>>(cnt, start, counter);
  k_scatter <<<(EE+255)/256, 256, 0, stream>>>(ei, start, fill, csr, srcp, tgtp);
  k_loop_div<<<(NN*32+255)/256, 256, 0, stream>>>(loop, cnt);
  k_xlxr1   <<<NN/8, 256, 0, stream>>>(h0, Wl1, bl1, Wr1, br1, xl1, xr1);
  k_score<256><<<EE/64, 256, 0, stream>>>(ee, csr, srcp, tgtp, xl1, xr1, We1, att1, esc);
  k_agg<4>  <<<NN, 256, 0, stream>>>(loop, cnt, start, srcp, xl1, xr1, We1, att1, bias1, esc, h1);
  k_xlxr2   <<<NN/8, 64, 0, stream>>>(h1, Wl2, bl2, Wr2, br2, xl2, xr2);
  k_score<64><<<EE/64, 256, 0, stream>>>(ee, csr, srcp, tgtp, xl2, xr2, We2, att2, esc);
  k_agg<1>  <<<NN, 64, 0, stream>>>(loop, cnt, start, srcp, xl2, xr2, We2, att2, bias2, esc, h2);
  k_pool    <<<(NN*64+255)/256, 256, 0, stream>>>(h2, batch, pooled, gcnt);
  k_out     <<<GG, 128, 0, stream>>>(pooled, gcnt, Wout, bout, out);
}

// Round 4
// 427.712 us; speedup vs baseline: 1.6426x; 1.0426x over previous
//
#include <hip/hip_runtime.h>
#include <hip/hip_bf16.h>

#define NN 20000
#define EE 320000
#define GG 256

__device__ __forceinline__ float lanebc(float v, int l){
  return __uint_as_float(__builtin_amdgcn_readlane(__float_as_uint(v), (unsigned)l));
}
__device__ __forceinline__ float wave_sum(float v){
  #pragma unroll
  for(int m=32;m>0;m>>=1) v += __shfl_xor(v, m, 64);
  return v;
}
__device__ __forceinline__ float wave_max(float v){
  #pragma unroll
  for(int m=32;m>0;m>>=1) v = fmaxf(v, __shfl_xor(v, m, 64));
  return v;
}

// ---------------- fold edge weights: Wf[9,F] = W_e[9,32]@We[32,F], bf[F] = be@We ----------------
template<int F>
__global__ void k_fold(const float* __restrict__ We9, const float* __restrict__ be,
                       const float* __restrict__ WeL, float* __restrict__ Wf, float* __restrict__ bf){
  const int c = threadIdx.x;  // F threads
  #pragma unroll
  for (int j=0;j<9;j++){
    float a = 0.f;
    #pragma unroll
    for (int k=0;k<32;k++) a += We9[j*32+k]*WeL[k*F+c];
    Wf[j*F+c] = a;
  }
  float b = 0.f;
  #pragma unroll
  for (int k=0;k<32;k++) b += be[k]*WeL[k*F+c];
  bf[c] = b;
}

// ---------------- node MLP: h0[N,64] ----------------
__global__ void k_node_mlp(const float* __restrict__ x, const float* __restrict__ Wcat,
                           const float* __restrict__ bcat, const float* __restrict__ Wini,
                           const float* __restrict__ bini, float* __restrict__ h0){
  const int t = blockIdx.x;
  const int c = threadIdx.x;   // 64
  __shared__ float xs[24];
  __shared__ float s[32];
  if (c < 24) xs[c] = x[t*24 + c];
  __syncthreads();
  if (c < 32){
    float a = bcat[c];
    #pragma unroll
    for(int k=0;k<16;k++) a += xs[k]*Wcat[k*32 + c];
    s[c] = fmaxf(a, 0.f);
  }
  __syncthreads();
  float a = bini[c];
  #pragma unroll
  for(int k=0;k<8;k++)  a += xs[16+k]*Wini[k*64 + c];
  #pragma unroll
  for(int k=0;k<32;k++) a += s[k]*Wini[(8+k)*64 + c];
  h0[t*64 + c] = fmaxf(a, 0.f);
}

// ---------------- per-target ea sums (for self-loop mean) + in-degree ----------------
__global__ void k_edge_acc(const int* __restrict__ ei, const float* __restrict__ ea,
                           float* __restrict__ loopA, int* __restrict__ cnt){
  const int g = blockIdx.x*16 + (threadIdx.x>>4);
  const int j = threadIdx.x & 15;
  if (g >= EE) return;
  const int t = ei[EE + g];
  if (j < 9)       atomicAdd(&loopA[t*12 + j], ea[(size_t)g*9 + j]);
  else if (j == 9) atomicAdd(&cnt[t], 1);
}

// ---------------- CSR bucket allocation (order-free, no scan) ----------------
__global__ void k_alloc(const int* __restrict__ cnt, int* __restrict__ start, int* __restrict__ counter){
  int i = blockIdx.x*blockDim.x + threadIdx.x;
  if (i < NN) start[i] = atomicAdd(counter, cnt[i]);
}

__global__ void k_scatter(const int* __restrict__ ei, const int* __restrict__ start,
                          int* __restrict__ fill, int* __restrict__ csr,
                          int* __restrict__ srcp, int* __restrict__ tgtp){
  int e = blockIdx.x*blockDim.x + threadIdx.x;
  if (e >= EE) return;
  int t = ei[EE + e];
  int p = start[t] + atomicAdd(&fill[t], 1);
  csr[p] = e;
  srcp[p] = ei[e];
  tgtp[p] = t;
}

// ---------------- xl/xr transform, layer1: [N,64]@[64,256] ----------------
__global__ void k_xlxr1(const float* __restrict__ h0, const float* __restrict__ Wl,
                        const float* __restrict__ bl, const float* __restrict__ Wr,
                        const float* __restrict__ br, float* __restrict__ xl, float* __restrict__ xr){
  const int n0 = blockIdx.x*8;
  __shared__ __align__(16) float hsT[64][8];
  for(int i=threadIdx.x;i<512;i+=256){ int n=i>>6, k=i&63; hsT[k][n] = h0[(n0+n)*64 + k]; }
  __syncthreads();
  const int c = threadIdx.x;   // 256
  float accl[8], accr[8];
  const float blv = bl[c], brv = br[c];
  #pragma unroll
  for(int n=0;n<8;n++){ accl[n]=blv; accr[n]=brv; }
  for(int k=0;k<64;k++){
    const float wl = Wl[k*256 + c];
    const float wr = Wr[k*256 + c];
    const float4 ha = *(const float4*)&hsT[k][0];
    const float4 hb = *(const float4*)&hsT[k][4];
    accl[0]+=ha.x*wl; accr[0]+=ha.x*wr; accl[1]+=ha.y*wl; accr[1]+=ha.y*wr;
    accl[2]+=ha.z*wl; accr[2]+=ha.z*wr; accl[3]+=ha.w*wl; accr[3]+=ha.w*wr;
    accl[4]+=hb.x*wl; accr[4]+=hb.x*wr; accl[5]+=hb.y*wl; accr[5]+=hb.y*wr;
    accl[6]+=hb.z*wl; accr[6]+=hb.z*wr; accl[7]+=hb.w*wl; accr[7]+=hb.w*wr;
  }
  #pragma unroll
  for(int n=0;n<8;n++){ xl[(n0+n)*256 + c] = accl[n]; xr[(n0+n)*256 + c] = accr[n]; }
}

// ---------------- xl/xr transform, layer2: [N,256]@[256,64] ----------------
__global__ void k_xlxr2(const float* __restrict__ h1, const float* __restrict__ Wl,
                        const float* __restrict__ bl, const float* __restrict__ Wr,
                        const float* __restrict__ br, float* __restrict__ xl, float* __restrict__ xr){
  const int n0 = blockIdx.x*8;
  __shared__ __align__(16) float hsT[256][8];
  for(int i=threadIdx.x;i<2048;i+=64){ int n=i>>8, k=i&255; hsT[k][n] = h1[(n0+n)*256 + k]; }
  __syncthreads();
  const int c = threadIdx.x;   // 64
  float accl[8], accr[8];
  const float blv = bl[c], brv = br[c];
  #pragma unroll
  for(int n=0;n<8;n++){ accl[n]=blv; accr[n]=brv; }
  for(int k=0;k<256;k++){
    const float wl = Wl[k*64 + c];
    const float wr = Wr[k*64 + c];
    const float4 ha = *(const float4*)&hsT[k][0];
    const float4 hb = *(const float4*)&hsT[k][4];
    accl[0]+=ha.x*wl; accr[0]+=ha.x*wr; accl[1]+=ha.y*wl; accr[1]+=ha.y*wr;
    accl[2]+=ha.z*wl; accr[2]+=ha.z*wr; accl[3]+=ha.w*wl; accr[3]+=ha.w*wr;
    accl[4]+=hb.x*wl; accr[4]+=hb.x*wr; accl[5]+=hb.y*wl; accr[5]+=hb.y*wr;
    accl[6]+=hb.z*wl; accr[6]+=hb.z*wr; accl[7]+=hb.w*wl; accr[7]+=hb.w*wr;
  }
  #pragma unroll
  for(int n=0;n<8;n++){ xl[(n0+n)*64 + c] = accl[n]; xr[(n0+n)*64 + c] = accr[n]; }
}

// ---------------- edge-parallel GATv2 scores (folded weights, K=9), CSR order ----------------
template<int F>
__global__ __launch_bounds__(256) void k_score(const float* __restrict__ ea, const int* __restrict__ csr,
                        const int* __restrict__ srcp, const int* __restrict__ tgtp,
                        const float* __restrict__ xl, const float* __restrict__ xr,
                        const float* __restrict__ Wf, const float* __restrict__ bf,
                        const float* __restrict__ att, float* __restrict__ esc)
{
  constexpr int HP  = (F == 256) ? 2 : 1;   // channel passes
  constexpr int CPL = (F == 256) ? 8 : 4;   // channels per lane per pass
  const int tid  = threadIdx.x;
  const int lane = tid & 63;
  const int w    = tid >> 6;
  const int p0   = blockIdx.x * 64;

  __shared__ float ea_sT[9][64];
  __shared__ float Wf_s[9*F];
  __shared__ float bf_s[F];
  __shared__ int csr_s[64], src_s[64], tgt_s[64];

  if (tid < 64) { csr_s[tid] = csr[p0+tid]; src_s[tid] = srcp[p0+tid]; tgt_s[tid] = tgtp[p0+tid]; }
  __syncthreads();
  for (int i = tid; i < 576; i += 256){ int j = i>>6, ed = i&63; ea_sT[j][ed] = ea[(size_t)csr_s[ed]*9 + j]; }
  for (int i = tid; i < (9*F)/4; i += 256) ((float4*)Wf_s)[i] = ((const float4*)Wf)[i];
  if (tid < F) bf_s[tid] = bf[tid];
  __syncthreads();

  const int g = lane >> 4, t = lane & 15;
  const int eb = w*16 + g*4;     // this lane's 4 edges

  #pragma unroll
  for (int hp = 0; hp < HP; ++hp) {
    const int c = hp*(F/HP) + t*CPL;
    float bfv[CPL];
    *(float4*)&bfv[0] = *(const float4*)&bf_s[c];
    if (CPL==8) *(float4*)&bfv[4] = *(const float4*)&bf_s[c+4];
    float acc[4][CPL];
    #pragma unroll
    for (int j=0;j<4;j++)
      #pragma unroll
      for(int q=0;q<CPL;q++) acc[j][q]=bfv[q];
    #pragma unroll
    for (int k=0;k<9;k++){
      const float4 ev = *(const float4*)&ea_sT[k][eb];
      float wv[CPL];
      *(float4*)&wv[0] = *(const float4*)&Wf_s[k*F + c];
      if (CPL==8) *(float4*)&wv[4] = *(const float4*)&Wf_s[k*F + c + 4];
      #pragma unroll
      for (int q=0;q<CPL;q++){
        acc[0][q] += ev.x*wv[q]; acc[1][q] += ev.y*wv[q];
        acc[2][q] += ev.z*wv[q]; acc[3][q] += ev.w*wv[q];
      }
    }
    float attv[CPL];
    *(float4*)&attv[0] = *(const float4*)&att[c];
    if (CPL==8) *(float4*)&attv[4] = *(const float4*)&att[c+4];
    float partial[4];
    #pragma unroll
    for (int j=0;j<4;j++){
      const int s  = src_s[eb+j];
      const int tg = tgt_s[eb+j];
      float xlv[CPL], xrv[CPL];
      *(float4*)&xlv[0] = *(const float4*)&xl[(size_t)s*F + c];
      *(float4*)&xrv[0] = *(const float4*)&xr[(size_t)tg*F + c];
      if (CPL==8){
        *(float4*)&xlv[4] = *(const float4*)&xl[(size_t)s*F + c + 4];
        *(float4*)&xrv[4] = *(const float4*)&xr[(size_t)tg*F + c + 4];
      }
      float sum = 0.f;
      #pragma unroll
      for (int q=0;q<CPL;q++){
        float m = acc[j][q] + xlv[q] + xrv[q];
        m = (m >= 0.f) ? m : 0.2f*m;
        sum += attv[q]*m;
      }
      partial[j] = sum;
    }
    #pragma unroll
    for (int j=0;j<4;j++){
      partial[j] += __shfl_xor(partial[j], 1, 64);
      partial[j] += __shfl_xor(partial[j], 2, 64);
      partial[j] += __shfl_xor(partial[j], 4, 64);
      if (F==64) partial[j] += __shfl_xor(partial[j], 8, 64);
    }
    if (F==256){
      if ((t & 7) == 0){
        const int h = hp*2 + (t>>3);
        #pragma unroll
        for (int j=0;j<4;j++) esc[(size_t)h*EE + p0 + eb + j] = partial[j];
      }
    } else {
      if (t == 0){
        #pragma unroll
        for (int j=0;j<4;j++) esc[p0 + eb + j] = partial[j];
      }
    }
  }
}

// ---------------- per-node softmax + aggregate (scores precomputed) ----------------
template<int HEADS>
__global__ void k_agg(const float* __restrict__ loopA, const int* __restrict__ cnt,
                      const int* __restrict__ start, const int* __restrict__ srcp,
                      const float* __restrict__ xl, const float* __restrict__ xr,
                      const float* __restrict__ Wf, const float* __restrict__ bf,
                      const float* __restrict__ att, const float* __restrict__ bias,
                      const float* __restrict__ esc, float* __restrict__ hout)
{
  const int t    = blockIdx.x;
  const int lane = threadIdx.x & 63;
  const int w    = threadIdx.x >> 6;
  const int F    = HEADS*64;
  const int c    = w*64 + lane;
  const int st = start[t], dg = cnt[t];
  const float* escw = esc + (size_t)w*EE;

  const float xlS = xl[(size_t)t*F + c];
  const float xrv = xr[(size_t)t*F + c];

  // self-loop score: ep = mean(ea_in)@Wf + bf  (== mean(ee)@We + be@We); dg==0 -> ep = 0
  float ep = 0.f;
  if (dg > 0){
    const float invc = 1.f/(float)dg;
    ep = bf[c];
    #pragma unroll
    for (int j=0;j<9;j++) ep += (loopA[t*12+j]*invc) * Wf[j*F + c];
  }
  float m = xlS + xrv + ep;
  m = (m >= 0.f) ? m : 0.2f*m;
  const float sSelf = wave_sum(att[c]*m);

  int sL = 0; float escv = -1e30f;
  if (lane < dg){ sL = srcp[st+lane]; escv = escw[st+lane]; }
  float mx = fmaxf(wave_max(escv), sSelf);
  for (int i=64;i<dg;i+=64){
    float v = (i+lane<dg) ? escw[st+i+lane] : -1e30f;
    mx = fmaxf(mx, wave_max(v));
  }
  const float pSelf = __expf(sSelf - mx);
  float preg = (lane < dg) ? __expf(escv - mx) : 0.f;
  float den = wave_sum(preg) + pSelf;
  float acc = pSelf * xlS;
  const int d1 = min(dg, 64);
  for (int i=0;i<d1;i++){
    const int s = __shfl(sL, i, 64);
    const float pp = lanebc(preg, i);
    acc += pp * xl[(size_t)s*F + c];
  }
  for (int i=64;i<dg;i++){
    const float pp = __expf(escw[st+i] - mx);
    den += pp;
    acc += pp * xl[(size_t)srcp[st+i]*F + c];
  }
  const float o = acc/(den + 1e-16f) + bias[c];
  hout[(size_t)t*F + c] = (o > 0.f) ? o : expm1f(o);
}

// ---------------- graph mean-pool + output projection ----------------
__global__ void k_pool(const float* __restrict__ h2, const int* __restrict__ batch,
                       float* __restrict__ pooled, int* __restrict__ gcnt){
  int i = blockIdx.x*blockDim.x + threadIdx.x;
  if (i >= NN*64) return;
  int node = i >> 6, c = i & 63;
  int g = batch[node];
  atomicAdd(&pooled[g*64 + c], h2[i]);
  if (c == 0) atomicAdd(&gcnt[g], 1);
}

__global__ void k_out(const float* __restrict__ pooled, const int* __restrict__ gcnt,
                      const float* __restrict__ Wout, const float* __restrict__ bout,
                      float* __restrict__ out){
  int g = blockIdx.x, o = threadIdx.x;   // 128
  float a = 0.f;
  for(int k=0;k<64;k++) a += pooled[g*64 + k] * Wout[k*128 + o];
  float inv = 1.f / fmaxf((float)gcnt[g], 1.f);
  out[g*128 + o] = a*inv + bout[o];
}

extern "C" void kernel_launch(void* const* d_in, const int* in_sizes, int n_in,
                              void* d_out, int out_size, void* d_ws, size_t ws_size,
                              hipStream_t stream) {
  const float* x    = (const float*)d_in[0];
  const int*   ei   = (const int*)  d_in[1];
  const float* ea   = (const float*)d_in[2];
  const int*   batch= (const int*)  d_in[3];
  const float* Wcat = (const float*)d_in[4];
  const float* bcat = (const float*)d_in[5];
  const float* We   = (const float*)d_in[6];
  const float* be   = (const float*)d_in[7];
  const float* Wini = (const float*)d_in[8];
  const float* bini = (const float*)d_in[9];
  const float* Wl1  = (const float*)d_in[10];
  const float* bl1  = (const float*)d_in[11];
  const float* Wr1  = (const float*)d_in[12];
  const float* br1  = (const float*)d_in[13];
  const float* We1  = (const float*)d_in[14];
  const float* att1 = (const float*)d_in[15];
  const float* bias1= (const float*)d_in[16];
  const float* Wl2  = (const float*)d_in[17];
  const float* bl2  = (const float*)d_in[18];
  const float* Wr2  = (const float*)d_in[19];
  const float* br2  = (const float*)d_in[20];
  const float* We2  = (const float*)d_in[21];
  const float* att2 = (const float*)d_in[22];
  const float* bias2= (const float*)d_in[23];
  const float* Wout = (const float*)d_in[24];
  const float* bout = (const float*)d_in[25];
  float* out = (float*)d_out;
  char* ws = (char*)d_ws;

  size_t off = 0;
  auto alloc = [&](size_t bytes)->char*{ char* p = ws + off; off += (bytes + 255) & ~(size_t)255; return p; };
  float* h0    = (float*)alloc((size_t)NN*64*4);
  float* loopA = (float*)alloc((size_t)NN*12*4);
  float* xl1   = (float*)alloc((size_t)NN*256*4);
  float* xr1   = (float*)alloc((size_t)NN*256*4);
  float* h1    = (float*)alloc((size_t)NN*256*4);
  float* xl2   = (float*)alloc((size_t)NN*64*4);
  float* xr2   = (float*)alloc((size_t)NN*64*4);
  float* h2    = (float*)alloc((size_t)NN*64*4);
  float* esc   = (float*)alloc((size_t)EE*4*4);
  float* Wf1   = (float*)alloc((size_t)9*256*4);
  float* bf1   = (float*)alloc((size_t)256*4);
  float* Wf2   = (float*)alloc((size_t)9*64*4);
  float* bf2   = (float*)alloc((size_t)64*4);
  int*   cnt   = (int*)  alloc((size_t)NN*4);
  int*   start = (int*)  alloc((size_t)NN*4);
  int*   fill  = (int*)  alloc((size_t)NN*4);
  int*   csr   = (int*)  alloc((size_t)EE*4);
  int*   srcp  = (int*)  alloc((size_t)EE*4);
  int*   tgtp  = (int*)  alloc((size_t)EE*4);
  int*   counter = (int*)alloc(256);
  float* pooled  = (float*)alloc((size_t)GG*64*4);
  int*   gcnt    = (int*)  alloc((size_t)GG*4);

  hipMemsetAsync(loopA,   0, (size_t)NN*12*4, stream);
  hipMemsetAsync(cnt,     0, (size_t)NN*4,    stream);
  hipMemsetAsync(fill,    0, (size_t)NN*4,    stream);
  hipMemsetAsync(counter, 0, 256,             stream);
  hipMemsetAsync(pooled,  0, (size_t)GG*64*4, stream);
  hipMemsetAsync(gcnt,    0, (size_t)GG*4,    stream);

  k_fold<256><<<1, 256, 0, stream>>>(We, be, We1, Wf1, bf1);
  k_fold<64> <<<1, 64, 0, stream>>>(We, be, We2, Wf2, bf2);
  k_node_mlp <<<NN, 64, 0, stream>>>(x, Wcat, bcat, Wini, bini, h0);
  k_edge_acc <<<EE/16, 256, 0, stream>>>(ei, ea, loopA, cnt);
  k_alloc    <<<(NN+255)/256, 256, 0, stream>>>(cnt, start, counter);
  k_scatter  <<<(EE+255)/256, 256, 0, stream>>>(ei, start, fill, csr, srcp, tgtp);
  k_xlxr1    <<<NN/8, 256, 0, stream>>>(h0, Wl1, bl1, Wr1, br1, xl1, xr1);
  k_score<256><<<EE/64, 256, 0, stream>>>(ea, csr, srcp, tgtp, xl1, xr1, Wf1, bf1, att1, esc);
  k_agg<4>   <<<NN, 256, 0, stream>>>(loopA, cnt, start, srcp, xl1, xr1, Wf1, bf1, att1, bias1, esc, h1);
  k_xlxr2    <<<NN/8, 64, 0, stream>>>(h1, Wl2, bl2, Wr2, br2, xl2, xr2);
  k_score<64><<<EE/64, 256, 0, stream>>>(ea, csr, srcp, tgtp, xl2, xr2, Wf2, bf2, att2, esc);
  k_agg<1>   <<<NN, 64, 0, stream>>>(loopA, cnt, start, srcp, xl2, xr2, Wf2, bf2, att2, bias2, esc, h2);
  k_pool     <<<(NN*64+255)/256, 256, 0, stream>>>(h2, batch, pooled, gcnt);
  k_out      <<<GG, 128, 0, stream>>>(pooled, gcnt, Wout, bout, out);
}